// Round 6
// baseline (4494.054 us; speedup 1.0000x reference)
//
#include <hip/hip_runtime.h>
#include <stdint.h>

#define TT 512
#define NB 32

typedef __attribute__((ext_vector_type(8))) short bf16x8;
typedef __attribute__((ext_vector_type(4))) float f32x4;

// ---- workspace layout (bytes) ----
#define O_XB   0ull            // x bf16            [16384,256]   8,388,608
#define O_W0   8388608ull      // pre_W0 bf16       [512,256]
#define O_W1   8650752ull      // pre_W1 bf16       [512,512]
#define O_WIH  9175040ull      // weight_ih bf16    [4096,512]
#define O_WHH  13369344ull     // weight_hh bf16    [4096,1024]
#define O_WA0  21757952ull     // act_W0 bf16       [512,1024]
#define O_WA1  22806528ull     // act_W1 bf16       [64,512]
#define O_WV0  22872064ull     // val_W0 bf16       [512,1024]
#define O_WV1  23920640ull     // val_W1 bf16       [1,512]
#define O_GB   23921664ull     // bias_ih+bias_hh fp32 [4096]
#define O_H1   23938048ull     // pre0 out bf16 [16384,512]; packet bufs during scan; act0 out after
#define O_U    40715264ull     // pre1 out bf16     [16384,512]  (reused for val0 out)
#define O_GX   57492480ull     // x_gates bf16      [t*32+b][4096] = 134,217,728 (v2 layout)
#define O_HS   191710208ull    // hs bf16           [16384,1024] 33,554,432
#define WS_NEED 225264640ull

__device__ __forceinline__ unsigned short f2bf(float f) {
  unsigned u = __builtin_bit_cast(unsigned, f);
  u = (u + 0x7fffu + ((u >> 16) & 1u)) >> 16;
  return (unsigned short)u;
}
__device__ __forceinline__ float bf2f_lo(unsigned w) { return __builtin_bit_cast(float, w << 16); }
__device__ __forceinline__ float bf2f_hi(unsigned w) { return __builtin_bit_cast(float, w & 0xffff0000u); }

__device__ __forceinline__ float dot8(uint4 a, uint4 b, float acc) {
  acc = fmaf(bf2f_lo(a.x), bf2f_lo(b.x), acc);
  acc = fmaf(bf2f_hi(a.x), bf2f_hi(b.x), acc);
  acc = fmaf(bf2f_lo(a.y), bf2f_lo(b.y), acc);
  acc = fmaf(bf2f_hi(a.y), bf2f_hi(b.y), acc);
  acc = fmaf(bf2f_lo(a.z), bf2f_lo(b.z), acc);
  acc = fmaf(bf2f_hi(a.z), bf2f_hi(b.z), acc);
  acc = fmaf(bf2f_lo(a.w), bf2f_lo(b.w), acc);
  acc = fmaf(bf2f_hi(a.w), bf2f_hi(b.w), acc);
  return acc;
}
__device__ __forceinline__ float sigf(float x) { return 1.f / (1.f + __expf(-x)); }
__device__ __forceinline__ float tanhf_(float x) { float e = __expf(2.f * x); return 1.f - 2.f / (e + 1.f); }

// ---- fp32 -> bf16 conversion of all inputs, + fused gate bias ----
__global__ void cvt_kernel(const float* __restrict__ x,  const float* __restrict__ w0,
                           const float* __restrict__ w1, const float* __restrict__ wih,
                           const float* __restrict__ whh, const float* __restrict__ wa0,
                           const float* __restrict__ wa1, const float* __restrict__ wv0,
                           const float* __restrict__ wv1, const float* __restrict__ bih,
                           const float* __restrict__ bhh, unsigned char* __restrict__ ws) {
  unsigned i = blockIdx.x * 256u + threadIdx.x;
  if (i >= 2991232u) return;
  const float* s; unsigned long long off; unsigned local;
  if      (i < 1048576u) { s = x;   off = O_XB;  local = i; }
  else if (i < 1081344u) { s = w0;  off = O_W0;  local = i - 1048576u; }
  else if (i < 1146880u) { s = w1;  off = O_W1;  local = i - 1081344u; }
  else if (i < 1671168u) { s = wih; off = O_WIH; local = i - 1146880u; }
  else if (i < 2719744u) { s = whh; off = O_WHH; local = i - 1671168u; }
  else if (i < 2850816u) { s = wa0; off = O_WA0; local = i - 2719744u; }
  else if (i < 2859008u) { s = wa1; off = O_WA1; local = i - 2850816u; }
  else if (i < 2990080u) { s = wv0; off = O_WV0; local = i - 2859008u; }
  else if (i < 2990208u) { s = wv1; off = O_WV1; local = i - 2990080u; }
  else {
    unsigned l2 = i - 2990208u;
    float4 a = ((const float4*)bih)[l2];
    float4 b = ((const float4*)bhh)[l2];
    float4 o; o.x = a.x + b.x; o.y = a.y + b.y; o.z = a.z + b.z; o.w = a.w + b.w;
    ((float4*)(ws + O_GB))[l2] = o;
    return;
  }
  float4 v = ((const float4*)s)[local];
  ushort4 o; o.x = f2bf(v.x); o.y = f2bf(v.y); o.z = f2bf(v.z); o.w = f2bf(v.w);
  ((ushort4*)(ws + off))[local] = o;
}

// ---- generic bf16 GEMM: C[M,N] = act(A[M,K] @ B[N,K]^T + bias) ----
// ILV=1: v2 layout — row (r&511)*NB + (r>>9), i.e. gx[t*32+b][4096].
template<int RELU, int ILV>
__global__ __launch_bounds__(256, 2) void gemm_bt(const unsigned short* __restrict__ A,
    const unsigned short* __restrict__ Bw, const float* __restrict__ bias,
    unsigned short* __restrict__ C, int M, int N, int K) {
  __shared__ unsigned short As[128 * 40];
  __shared__ unsigned short Bs[128 * 40];
  const int tid = threadIdx.x;
  const int l = tid & 63, w = tid >> 6;
  const int wm = (w >> 1) * 64, wn = (w & 1) * 64;
  const int m0 = blockIdx.y * 128, n0 = blockIdx.x * 128;
  const int sr = tid >> 2;
  const int sk = (tid & 3) * 8;
  const int fr = l & 15;
  const int kf = (l >> 4) * 8;
  f32x4 acc[4][4] = {};
  for (int kb = 0; kb < K; kb += 32) {
    uint4 a0 = *(const uint4*)(A + (size_t)(m0 + sr) * K + kb + sk);
    uint4 a1 = *(const uint4*)(A + (size_t)(m0 + sr + 64) * K + kb + sk);
    uint4 b0 = *(const uint4*)(Bw + (size_t)(n0 + sr) * K + kb + sk);
    uint4 b1 = *(const uint4*)(Bw + (size_t)(n0 + sr + 64) * K + kb + sk);
    __syncthreads();
    *(uint4*)(As + sr * 40 + sk) = a0;
    *(uint4*)(As + (sr + 64) * 40 + sk) = a1;
    *(uint4*)(Bs + sr * 40 + sk) = b0;
    *(uint4*)(Bs + (sr + 64) * 40 + sk) = b1;
    __syncthreads();
    bf16x8 af[4], bfr[4];
    #pragma unroll
    for (int mt = 0; mt < 4; mt++)
      af[mt] = __builtin_bit_cast(bf16x8, *(const uint4*)(As + (wm + mt * 16 + fr) * 40 + kf));
    #pragma unroll
    for (int nt = 0; nt < 4; nt++)
      bfr[nt] = __builtin_bit_cast(bf16x8, *(const uint4*)(Bs + (wn + nt * 16 + fr) * 40 + kf));
    #pragma unroll
    for (int mt = 0; mt < 4; mt++)
      #pragma unroll
      for (int nt = 0; nt < 4; nt++)
        acc[mt][nt] = __builtin_amdgcn_mfma_f32_16x16x32_bf16(af[mt], bfr[nt], acc[mt][nt], 0, 0, 0);
  }
  const int rq = (l >> 4) * 4;
  #pragma unroll
  for (int nt = 0; nt < 4; nt++) {
    int n = n0 + wn + nt * 16 + fr;
    float bv = bias[n];
    #pragma unroll
    for (int mt = 0; mt < 4; mt++) {
      int rb = m0 + wm + mt * 16 + rq;
      #pragma unroll
      for (int i = 0; i < 4; i++) {
        float v = acc[mt][nt][i] + bv;
        if (RELU) v = fmaxf(v, 0.f);
        int r = rb + i;
        size_t orow = ILV ? ((size_t)(r & (TT - 1)) * NB + (size_t)(r >> 9)) : (size_t)r;
        C[orow * (size_t)N + n] = f2bf(v);
      }
    }
  }
}

// ---- persistent LSTM scan v6: v5 + masked cheap retries ----
// Identical to v5 (2 groups x 64 blocks, 16 dims/block, tagged packets,
// per-dword validation) except the poll: the full 32-packet set is read
// once; retries re-load ONLY the ks-groups whose tags failed (8-bit pending
// mask per lane, divergent predicated loads). v5's regression was retry
// traffic (full 32 KB/block re-read every ~1100 cyc) saturating the
// L3/fabric path; straggler-only reloads cut speculative traffic ~10x.
__global__ __launch_bounds__(256, 1) void lstm_scan(
    const unsigned short* __restrict__ whh,
    const unsigned short* __restrict__ gx,
    unsigned* __restrict__ pk,
    unsigned short* __restrict__ hs) {
  __shared__ float part[4096];   // [w][q][lane][4]
  const int tid = threadIdx.x;
  const int l = tid & 63, w = tid >> 6;
  const int g = blockIdx.x >> 6;   // batch-group
  const int s = blockIdx.x & 63;   // dim slice: dims [s*16, s*16+16)
  const int fr = l & 15, kf = (l >> 4) * 8;

  // resident weights: 4 gates x 16 rows x (this wave's K=256) = 128 VGPRs
  bf16x8 wf[4][8];
  #pragma unroll
  for (int q = 0; q < 4; q++)
    #pragma unroll
    for (int ks = 0; ks < 8; ks++) {
      int row = q * 1024 + s * 16 + fr;
      int k = w * 256 + ks * 32 + kf;
      wf[q][ks] = __builtin_bit_cast(bf16x8, *(const uint4*)(whh + (size_t)row * 1024 + k));
    }

  const int pm = tid >> 3;        // batch (tid<128)
  const int j2 = (tid & 7) * 2;   // dim pair within slice
  const int kh = w * 128 + (kf >> 1);   // ull index base into a packet row
  float c0 = 0.f, c1 = 0.f;

  for (int t = 0; t < TT; t++) {
    // gx prefetch (v2 layout/reads, independent of h)
    unsigned gxw0 = 0, gxw1 = 0, gxw2 = 0, gxw3 = 0;
    if (tid < 128) {
      const unsigned* gp = (const unsigned*)(gx + ((size_t)t * NB + g * 16 + pm) * 4096 + s * 16 + j2);
      gxw0 = gp[0]; gxw1 = gp[512]; gxw2 = gp[1024]; gxw3 = gp[1536];
    }

    // validated h read: full read once, then straggler-only masked retries.
    const unsigned long long* hq =
        (const unsigned long long*)(pk + (((size_t)(g * 2 + (t & 1)) * 16 + fr) << 10));
    unsigned long long raw[32];
    const unsigned expv = ((unsigned)t) << 16;
    #pragma unroll
    for (int ks = 0; ks < 8; ks++)
      #pragma unroll
      for (int j = 0; j < 4; j++)
        raw[ks * 4 + j] = __hip_atomic_load(hq + kh + ks * 16 + j,
                                            __ATOMIC_RELAXED, __HIP_MEMORY_SCOPE_AGENT);
    unsigned pend = 0xffu;
    while (true) {
      #pragma unroll
      for (int ks = 0; ks < 8; ks++) {
        if (pend & (1u << ks)) {
          unsigned m = 0;
          #pragma unroll
          for (int j = 0; j < 4; j++) {
            unsigned lo = (unsigned)raw[ks * 4 + j];
            unsigned hi = (unsigned)(raw[ks * 4 + j] >> 32);
            m |= ((lo ^ expv) | (hi ^ expv)) & 0xffff0000u;
          }
          if (m == 0u) {
            pend &= ~(1u << ks);
          } else {
            #pragma unroll
            for (int j = 0; j < 4; j++)
              raw[ks * 4 + j] = __hip_atomic_load(hq + kh + ks * 16 + j,
                                                  __ATOMIC_RELAXED, __HIP_MEMORY_SCOPE_AGENT);
          }
        }
      }
      if (!__any((int)(pend != 0u))) break;
      __builtin_amdgcn_s_sleep(1);
    }

    // unpack packets -> bf16 A-fragments (dims w*256+ks*32+kf+0..7)
    bf16x8 hf[8];
    #pragma unroll
    for (int ks = 0; ks < 8; ks++) {
      #pragma unroll
      for (int j = 0; j < 4; j++) {
        unsigned long long r_ = raw[ks * 4 + j];
        hf[ks][2 * j]     = (short)(unsigned short)(r_ & 0xffffu);
        hf[ks][2 * j + 1] = (short)(unsigned short)((r_ >> 32) & 0xffffu);
      }
    }
    f32x4 acc[4] = {};
    #pragma unroll
    for (int ks = 0; ks < 8; ks++)
      #pragma unroll
      for (int q = 0; q < 4; q++)
        acc[q] = __builtin_amdgcn_mfma_f32_16x16x32_bf16(hf[ks], wf[q][ks], acc[q], 0, 0, 0);
    __syncthreads();   // (A) prev step's part reads complete before overwrite
    #pragma unroll
    for (int q = 0; q < 4; q++)
      *(f32x4*)(&part[((w * 4 + q) * 64 + l) * 4]) = acc[q];
    __syncthreads();   // (B)

    if (tid < 128) {
      const int lane0 = (pm >> 2) * 16 + j2;
      const int reg = pm & 3;
      unsigned gxw[4] = {gxw0, gxw1, gxw2, gxw3};
      float gv[4][2];
      #pragma unroll
      for (int q = 0; q < 4; q++) {
        float v0 = bf2f_lo(gxw[q]);
        float v1 = bf2f_hi(gxw[q]);
        #pragma unroll
        for (int ww = 0; ww < 4; ww++) {
          v0 += part[((ww * 4 + q) * 64 + lane0) * 4 + reg];
          v1 += part[((ww * 4 + q) * 64 + lane0 + 1) * 4 + reg];
        }
        gv[q][0] = v0; gv[q][1] = v1;
      }
      float si0 = sigf(gv[0][0]), si1 = sigf(gv[0][1]);
      float sf0 = sigf(gv[1][0]), sf1 = sigf(gv[1][1]);
      float tg0 = tanhf_(gv[2][0]), tg1 = tanhf_(gv[2][1]);
      float so0 = sigf(gv[3][0]), so1 = sigf(gv[3][1]);
      c0 = sf0 * c0 + si0 * tg0;
      c1 = sf1 * c1 + si1 * tg1;
      float h0 = so0 * tanhf_(c0);
      float h1 = so1 * tanhf_(c1);
      unsigned hb0 = (unsigned)f2bf(h0), hb1 = (unsigned)f2bf(h1);
      unsigned tagw = ((unsigned)(t + 1)) << 16;
      unsigned long long pkt = (unsigned long long)(hb0 | tagw) |
                               ((unsigned long long)(hb1 | tagw) << 32);
      unsigned long long* dst = (unsigned long long*)(
          pk + (((size_t)(g * 2 + ((t + 1) & 1)) * 16 + pm) << 10) + s * 16 + j2);
      __hip_atomic_store(dst, pkt, __ATOMIC_RELAXED, __HIP_MEMORY_SCOPE_AGENT);
      *(unsigned*)(hs + ((size_t)(g * 16 + pm) * TT + t) * 1024 + s * 16 + j2) =
          hb0 | (hb1 << 16);
    }
  }
}

// ---- policy head: logits[16384,64] + softmax, fused ----
__global__ __launch_bounds__(512, 1) void act1_softmax(const unsigned short* __restrict__ Aa,
    const unsigned short* __restrict__ W1, const float* __restrict__ b1,
    float* __restrict__ out) {
  __shared__ unsigned short wl[64 * 512];
  const int tid = threadIdx.x;
  #pragma unroll
  for (int r = 0; r < 8; r++) {
    int e = r * 512 + tid;
    int col = e >> 6, kc = e & 63;
    *(uint4*)(wl + ((size_t)kc * 64 + col) * 8) = *(const uint4*)(W1 + (size_t)col * 512 + kc * 8);
  }
  __syncthreads();
  const int l = tid & 63, w = tid >> 6;
  size_t row = (size_t)blockIdx.x * 8 + w;
  const unsigned short* ar = Aa + row * 512;
  float acc = 0.f;
  for (int kc = 0; kc < 64; kc++) {
    uint4 au = *(const uint4*)(ar + kc * 8);
    uint4 wu = *(const uint4*)(wl + ((size_t)kc * 64 + l) * 8);
    acc = dot8(au, wu, acc);
  }
  float logit = acc + b1[l];
  float mx = logit;
  #pragma unroll
  for (int off = 32; off >= 1; off >>= 1) mx = fmaxf(mx, __shfl_xor(mx, off));
  float e = __expf(logit - mx);
  float ssum = e;
  #pragma unroll
  for (int off = 32; off >= 1; off >>= 1) ssum += __shfl_xor(ssum, off);
  out[row * 64 + l] = e / ssum;
}

// ---- value head: wave-per-row dot over K=512 ----
__global__ __launch_bounds__(256, 4) void val1_kernel(const unsigned short* __restrict__ V,
    const unsigned short* __restrict__ w1, const float* __restrict__ b1,
    float* __restrict__ out) {
  const int tid = threadIdx.x;
  const int l = tid & 63, w = tid >> 6;
  size_t row = (size_t)blockIdx.x * 4 + w;
  uint4 vu = *(const uint4*)(V + row * 512 + l * 8);
  uint4 wu = *(const uint4*)(w1 + l * 8);
  float s = dot8(vu, wu, 0.f);
  #pragma unroll
  for (int off = 32; off >= 1; off >>= 1) s += __shfl_xor(s, off);
  if (l == 0) out[1048576u + row] = s + b1[0];
}

extern "C" void kernel_launch(void* const* d_in, const int* in_sizes, int n_in,
                              void* d_out, int out_size, void* d_ws, size_t ws_size,
                              hipStream_t stream) {
  (void)in_sizes; (void)n_in; (void)out_size;
  if (ws_size < WS_NEED) return;
  const float* x   = (const float*)d_in[0];
  const float* pw0 = (const float*)d_in[1];
  const float* pb0 = (const float*)d_in[2];
  const float* pw1 = (const float*)d_in[3];
  const float* pb1 = (const float*)d_in[4];
  const float* wih = (const float*)d_in[5];
  const float* whh = (const float*)d_in[6];
  const float* bih = (const float*)d_in[7];
  const float* bhh = (const float*)d_in[8];
  const float* aw0 = (const float*)d_in[9];
  const float* ab0 = (const float*)d_in[10];
  const float* aw1 = (const float*)d_in[11];
  const float* ab1 = (const float*)d_in[12];
  const float* vw0 = (const float*)d_in[13];
  const float* vb0 = (const float*)d_in[14];
  const float* vw1 = (const float*)d_in[15];
  const float* vb1 = (const float*)d_in[16];
  unsigned char* ws = (unsigned char*)d_ws;
  float* out = (float*)d_out;

  const unsigned short* xb   = (const unsigned short*)(ws + O_XB);
  const unsigned short* w0b  = (const unsigned short*)(ws + O_W0);
  const unsigned short* w1b  = (const unsigned short*)(ws + O_W1);
  const unsigned short* wihb = (const unsigned short*)(ws + O_WIH);
  const unsigned short* whhb = (const unsigned short*)(ws + O_WHH);
  const unsigned short* wa0b = (const unsigned short*)(ws + O_WA0);
  const unsigned short* wa1b = (const unsigned short*)(ws + O_WA1);
  const unsigned short* wv0b = (const unsigned short*)(ws + O_WV0);
  const unsigned short* wv1b = (const unsigned short*)(ws + O_WV1);
  const float* gbp = (const float*)(ws + O_GB);
  unsigned short* h1b = (unsigned short*)(ws + O_H1);
  unsigned short* ub  = (unsigned short*)(ws + O_U);
  unsigned short* gxb = (unsigned short*)(ws + O_GX);
  unsigned short* hsb = (unsigned short*)(ws + O_HS);
  unsigned* pkb = (unsigned*)(ws + O_H1);   // packet bufs in dead h1 region
  unsigned short* aab = h1b;                // act0 output (after scan)
  unsigned short* vvb = ub;                 // val0 output

  cvt_kernel<<<11685, 256, 0, stream>>>(x, pw0, pw1, wih, whh, aw0, aw1, vw0, vw1, bih, bhh, ws);
  gemm_bt<1, 0><<<dim3(4, 128), 256, 0, stream>>>(xb, w0b, pb0, h1b, 16384, 512, 256);
  gemm_bt<0, 0><<<dim3(4, 128), 256, 0, stream>>>(h1b, w1b, pb1, ub, 16384, 512, 512);
  gemm_bt<0, 1><<<dim3(32, 128), 256, 0, stream>>>(ub, wihb, gbp, gxb, 16384, 4096, 512);
  // zero packet buffers: tag 0 == initial h state (h1 region is dead now)
  hipMemsetAsync(ws + O_H1, 0, 4 * 16 * 1024 * 4, stream);
  {
    const unsigned short* a_whh = whhb;
    const unsigned short* a_gx  = gxb;
    unsigned*       a_pk = pkb;
    unsigned short* a_hs = hsb;
    void* args[4] = { (void*)&a_whh, (void*)&a_gx, (void*)&a_pk, (void*)&a_hs };
    hipLaunchCooperativeKernel((void*)lstm_scan, dim3(128), dim3(256), args, 0, stream);
  }
  gemm_bt<1, 0><<<dim3(4, 128), 256, 0, stream>>>(hsb, wa0b, ab0, aab, 16384, 512, 1024);
  gemm_bt<1, 0><<<dim3(4, 128), 256, 0, stream>>>(hsb, wv0b, vb0, vvb, 16384, 512, 1024);
  act1_softmax<<<2048, 512, 0, stream>>>(aab, wa1b, ab1, out);
  val1_kernel<<<4096, 256, 0, stream>>>(vvb, wv1b, vb1, out);
}

// Round 7
// 2350.093 us; speedup vs baseline: 1.9123x; 1.9123x over previous
//
#include <hip/hip_runtime.h>
#include <stdint.h>

#define TT 512
#define NB 32

typedef __attribute__((ext_vector_type(8))) short bf16x8;
typedef __attribute__((ext_vector_type(4))) float f32x4;

// ---- workspace layout (bytes) ----
#define O_XB   0ull            // x bf16            [16384,256]   8,388,608
#define O_W0   8388608ull      // pre_W0 bf16       [512,256]
#define O_W1   8650752ull      // pre_W1 bf16       [512,512]
#define O_WIH  9175040ull      // weight_ih bf16    [4096,512]
#define O_WHH  13369344ull     // weight_hh bf16    [4096,1024]
#define O_WA0  21757952ull     // act_W0 bf16       [512,1024]
#define O_WA1  22806528ull     // act_W1 bf16       [64,512]
#define O_WV0  22872064ull     // val_W0 bf16       [512,1024]
#define O_WV1  23920640ull     // val_W1 bf16       [1,512]
#define O_GB   23921664ull     // bias_ih+bias_hh fp32 [4096]
#define O_H1   23938048ull     // pre0 out bf16 [16384,512]; h-bufs+flags during scan; act0 out after
#define O_U    40715264ull     // pre1 out bf16     [16384,512]  (reused for val0 out)
#define O_GX   57492480ull     // x_gates bf16      [t*32+b][4096] = 134,217,728 (v2 layout)
#define O_HS   191710208ull    // hs bf16           [16384,1024] 33,554,432
#define WS_NEED 225264640ull

__device__ __forceinline__ unsigned short f2bf(float f) {
  unsigned u = __builtin_bit_cast(unsigned, f);
  u = (u + 0x7fffu + ((u >> 16) & 1u)) >> 16;
  return (unsigned short)u;
}
__device__ __forceinline__ float bf2f_lo(unsigned w) { return __builtin_bit_cast(float, w << 16); }
__device__ __forceinline__ float bf2f_hi(unsigned w) { return __builtin_bit_cast(float, w & 0xffff0000u); }

__device__ __forceinline__ float dot8(uint4 a, uint4 b, float acc) {
  acc = fmaf(bf2f_lo(a.x), bf2f_lo(b.x), acc);
  acc = fmaf(bf2f_hi(a.x), bf2f_hi(b.x), acc);
  acc = fmaf(bf2f_lo(a.y), bf2f_lo(b.y), acc);
  acc = fmaf(bf2f_hi(a.y), bf2f_hi(b.y), acc);
  acc = fmaf(bf2f_lo(a.z), bf2f_lo(b.z), acc);
  acc = fmaf(bf2f_hi(a.z), bf2f_hi(b.z), acc);
  acc = fmaf(bf2f_lo(a.w), bf2f_lo(b.w), acc);
  acc = fmaf(bf2f_hi(a.w), bf2f_hi(b.w), acc);
  return acc;
}
__device__ __forceinline__ float sigf(float x) { return 1.f / (1.f + __expf(-x)); }
__device__ __forceinline__ float tanhf_(float x) { float e = __expf(2.f * x); return 1.f - 2.f / (e + 1.f); }

// ---- fp32 -> bf16 conversion of all inputs, + fused gate bias ----
__global__ void cvt_kernel(const float* __restrict__ x,  const float* __restrict__ w0,
                           const float* __restrict__ w1, const float* __restrict__ wih,
                           const float* __restrict__ whh, const float* __restrict__ wa0,
                           const float* __restrict__ wa1, const float* __restrict__ wv0,
                           const float* __restrict__ wv1, const float* __restrict__ bih,
                           const float* __restrict__ bhh, unsigned char* __restrict__ ws) {
  unsigned i = blockIdx.x * 256u + threadIdx.x;
  if (i >= 2991232u) return;
  const float* s; unsigned long long off; unsigned local;
  if      (i < 1048576u) { s = x;   off = O_XB;  local = i; }
  else if (i < 1081344u) { s = w0;  off = O_W0;  local = i - 1048576u; }
  else if (i < 1146880u) { s = w1;  off = O_W1;  local = i - 1081344u; }
  else if (i < 1671168u) { s = wih; off = O_WIH; local = i - 1146880u; }
  else if (i < 2719744u) { s = whh; off = O_WHH; local = i - 1671168u; }
  else if (i < 2850816u) { s = wa0; off = O_WA0; local = i - 2719744u; }
  else if (i < 2859008u) { s = wa1; off = O_WA1; local = i - 2850816u; }
  else if (i < 2990080u) { s = wv0; off = O_WV0; local = i - 2859008u; }
  else if (i < 2990208u) { s = wv1; off = O_WV1; local = i - 2990080u; }
  else {
    unsigned l2 = i - 2990208u;
    float4 a = ((const float4*)bih)[l2];
    float4 b = ((const float4*)bhh)[l2];
    float4 o; o.x = a.x + b.x; o.y = a.y + b.y; o.z = a.z + b.z; o.w = a.w + b.w;
    ((float4*)(ws + O_GB))[l2] = o;
    return;
  }
  float4 v = ((const float4*)s)[local];
  ushort4 o; o.x = f2bf(v.x); o.y = f2bf(v.y); o.z = f2bf(v.z); o.w = f2bf(v.w);
  ((ushort4*)(ws + off))[local] = o;
}

// ---- generic bf16 GEMM: C[M,N] = act(A[M,K] @ B[N,K]^T + bias) ----
// ILV=1: v2 layout — row (r&511)*NB + (r>>9), i.e. gx[t*32+b][4096].
template<int RELU, int ILV>
__global__ __launch_bounds__(256, 2) void gemm_bt(const unsigned short* __restrict__ A,
    const unsigned short* __restrict__ Bw, const float* __restrict__ bias,
    unsigned short* __restrict__ C, int M, int N, int K) {
  __shared__ unsigned short As[128 * 40];
  __shared__ unsigned short Bs[128 * 40];
  const int tid = threadIdx.x;
  const int l = tid & 63, w = tid >> 6;
  const int wm = (w >> 1) * 64, wn = (w & 1) * 64;
  const int m0 = blockIdx.y * 128, n0 = blockIdx.x * 128;
  const int sr = tid >> 2;
  const int sk = (tid & 3) * 8;
  const int fr = l & 15;
  const int kf = (l >> 4) * 8;
  f32x4 acc[4][4] = {};
  for (int kb = 0; kb < K; kb += 32) {
    uint4 a0 = *(const uint4*)(A + (size_t)(m0 + sr) * K + kb + sk);
    uint4 a1 = *(const uint4*)(A + (size_t)(m0 + sr + 64) * K + kb + sk);
    uint4 b0 = *(const uint4*)(Bw + (size_t)(n0 + sr) * K + kb + sk);
    uint4 b1 = *(const uint4*)(Bw + (size_t)(n0 + sr + 64) * K + kb + sk);
    __syncthreads();
    *(uint4*)(As + sr * 40 + sk) = a0;
    *(uint4*)(As + (sr + 64) * 40 + sk) = a1;
    *(uint4*)(Bs + sr * 40 + sk) = b0;
    *(uint4*)(Bs + (sr + 64) * 40 + sk) = b1;
    __syncthreads();
    bf16x8 af[4], bfr[4];
    #pragma unroll
    for (int mt = 0; mt < 4; mt++)
      af[mt] = __builtin_bit_cast(bf16x8, *(const uint4*)(As + (wm + mt * 16 + fr) * 40 + kf));
    #pragma unroll
    for (int nt = 0; nt < 4; nt++)
      bfr[nt] = __builtin_bit_cast(bf16x8, *(const uint4*)(Bs + (wn + nt * 16 + fr) * 40 + kf));
    #pragma unroll
    for (int mt = 0; mt < 4; mt++)
      #pragma unroll
      for (int nt = 0; nt < 4; nt++)
        acc[mt][nt] = __builtin_amdgcn_mfma_f32_16x16x32_bf16(af[mt], bfr[nt], acc[mt][nt], 0, 0, 0);
  }
  const int rq = (l >> 4) * 4;
  #pragma unroll
  for (int nt = 0; nt < 4; nt++) {
    int n = n0 + wn + nt * 16 + fr;
    float bv = bias[n];
    #pragma unroll
    for (int mt = 0; mt < 4; mt++) {
      int rb = m0 + wm + mt * 16 + rq;
      #pragma unroll
      for (int i = 0; i < 4; i++) {
        float v = acc[mt][nt][i] + bv;
        if (RELU) v = fmaxf(v, 0.f);
        int r = rb + i;
        size_t orow = ILV ? ((size_t)(r & (TT - 1)) * NB + (size_t)(r >> 9)) : (size_t)r;
        C[orow * (size_t)N + n] = f2bf(v);
      }
    }
  }
}

// ---- persistent LSTM scan v7: v2 flag handshake + consumer-coalesced h ----
// Reverts to round-2's proven structure (2 groups x 64 blocks, 16 dims/block,
// flag detect by wave 0, 3 barriers). Two local fixes:
//  (1) h buffer stored in consumer-fragment order [buf][wave][ks][lane]
//      (uint4 per (ks,lane)) -> bulk read is fully coalesced (v2 gathered
//      8-B words at 32-B stride over 16 rows: ~4x line overfetch).
//  (2) hs store moved AFTER the flag store: the vmcnt(0) drain before the
//      flag no longer waits on the HBM writeback ack; hs latency overlaps
//      the next step instead of sitting on the critical path.
__global__ __launch_bounds__(256, 1) void lstm_scan(
    const unsigned short* __restrict__ whh,
    const unsigned short* __restrict__ gx,
    unsigned* __restrict__ pk,          // 4 bufs x 8192 u32 (32 KB) + flags
    unsigned short* __restrict__ hs) {
  __shared__ float part[4096];   // [w][q][lane][4]
  const int tid = threadIdx.x;
  const int l = tid & 63, w = tid >> 6;
  const int g = blockIdx.x >> 6;   // batch-group
  const int s = blockIdx.x & 63;   // dim slice: dims [s*16, s*16+16)
  const int fr = l & 15, kf = (l >> 4) * 8;

  // resident weights: 4 gates x 16 rows x (this wave's K=256) = 128 VGPRs
  bf16x8 wf[4][8];
  #pragma unroll
  for (int q = 0; q < 4; q++)
    #pragma unroll
    for (int ks = 0; ks < 8; ks++) {
      int row = q * 1024 + s * 16 + fr;
      int k = w * 256 + ks * 32 + kf;
      wf[q][ks] = __builtin_bit_cast(bf16x8, *(const uint4*)(whh + (size_t)row * 1024 + k));
    }

  const int pm = tid >> 3;        // batch (tid<128)
  const int j2 = (tid & 7) * 2;   // dim pair within slice
  // producer slot in consumer-fragment layout for global dim D0 = s*16+j2:
  const int D0  = s * 16 + j2;
  const int pw  = D0 >> 8;             // consumer wave
  const int pr  = D0 & 255;
  const int pks = pr >> 5;             // consumer ks
  const int pkfg= (pr & 31) >> 3;      // consumer lane group
  const int pjj = (pr & 7) >> 1;       // u32 slot within uint4
  const unsigned pidx = ((unsigned)((pw * 8 + pks) * 64 + pkfg * 16 + pm) << 2) + pjj;

  unsigned* flags = pk + 32768;        // after 4 x 8192 u32 buffers
  unsigned* myflag = flags + (size_t)(g * 64 + s) * 8;
  const unsigned* pollp = flags + (size_t)(g * 64 + l) * 8;
  float c0 = 0.f, c1 = 0.f;

  for (int t = 0; t < TT; t++) {
    // gx prefetch (v2 layout, independent of h)
    unsigned gxw0 = 0, gxw1 = 0, gxw2 = 0, gxw3 = 0;
    if (tid < 128) {
      const unsigned* gp = (const unsigned*)(gx + ((size_t)t * NB + g * 16 + pm) * 4096 + s * 16 + j2);
      gxw0 = gp[0]; gxw1 = gp[512]; gxw2 = gp[1024]; gxw3 = gp[1536];
    }
    if (t > 0 && w == 0) {
      while (true) {
        unsigned f = __hip_atomic_load(pollp, __ATOMIC_RELAXED, __HIP_MEMORY_SCOPE_AGENT);
        if (!__any((int)(f < (unsigned)t))) break;
        __builtin_amdgcn_s_sleep(1);
      }
    }
    __syncthreads();
    asm volatile("" ::: "memory");

    // coalesced bulk h read: wave w's slice is contiguous [w*2048 .. +2048) ull
    const unsigned long long* hq =
        (const unsigned long long*)(pk + (size_t)(g * 2 + (t & 1)) * 8192);
    bf16x8 hf[8];
    #pragma unroll
    for (int ks = 0; ks < 8; ks++) {
      size_t i2 = ((size_t)(w * 8 + ks) * 64 + l) * 2;
      unsigned long long lo = __hip_atomic_load(hq + i2,     __ATOMIC_RELAXED, __HIP_MEMORY_SCOPE_AGENT);
      unsigned long long hi = __hip_atomic_load(hq + i2 + 1, __ATOMIC_RELAXED, __HIP_MEMORY_SCOPE_AGENT);
      uint4 u; u.x = (unsigned)lo; u.y = (unsigned)(lo >> 32);
      u.z = (unsigned)hi; u.w = (unsigned)(hi >> 32);
      hf[ks] = __builtin_bit_cast(bf16x8, u);
    }
    f32x4 acc[4] = {};
    #pragma unroll
    for (int ks = 0; ks < 8; ks++)
      #pragma unroll
      for (int q = 0; q < 4; q++)
        acc[q] = __builtin_amdgcn_mfma_f32_16x16x32_bf16(hf[ks], wf[q][ks], acc[q], 0, 0, 0);
    #pragma unroll
    for (int q = 0; q < 4; q++)
      *(f32x4*)(&part[((w * 4 + q) * 64 + l) * 4]) = acc[q];
    __syncthreads();

    unsigned hb01 = 0;
    if (tid < 128) {
      const int lane0 = (pm >> 2) * 16 + j2;
      const int reg = pm & 3;
      unsigned gxw[4] = {gxw0, gxw1, gxw2, gxw3};
      float gv[4][2];
      #pragma unroll
      for (int q = 0; q < 4; q++) {
        float v0 = bf2f_lo(gxw[q]);
        float v1 = bf2f_hi(gxw[q]);
        #pragma unroll
        for (int ww = 0; ww < 4; ww++) {
          v0 += part[((ww * 4 + q) * 64 + lane0) * 4 + reg];
          v1 += part[((ww * 4 + q) * 64 + lane0 + 1) * 4 + reg];
        }
        gv[q][0] = v0; gv[q][1] = v1;
      }
      float si0 = sigf(gv[0][0]), si1 = sigf(gv[0][1]);
      float sf0 = sigf(gv[1][0]), sf1 = sigf(gv[1][1]);
      float tg0 = tanhf_(gv[2][0]), tg1 = tanhf_(gv[2][1]);
      float so0 = sigf(gv[3][0]), so1 = sigf(gv[3][1]);
      c0 = sf0 * c0 + si0 * tg0;
      c1 = sf1 * c1 + si1 * tg1;
      float h0 = so0 * tanhf_(c0);
      float h1 = so1 * tanhf_(c1);
      hb01 = (unsigned)f2bf(h0) | ((unsigned)f2bf(h1) << 16);
      unsigned* dst = pk + (size_t)(g * 2 + ((t + 1) & 1)) * 8192 + pidx;
      __hip_atomic_store(dst, hb01, __ATOMIC_RELAXED, __HIP_MEMORY_SCOPE_AGENT);
      asm volatile("s_waitcnt vmcnt(0)" ::: "memory");  // drain h store only
    }
    __syncthreads();   // all producer waves drained before flag
    if (tid == 0)
      __hip_atomic_store(myflag, (unsigned)(t + 1), __ATOMIC_RELAXED, __HIP_MEMORY_SCOPE_AGENT);
    // hs store AFTER flag: overlaps with the next step, off the critical path
    if (tid < 128)
      *(unsigned*)(hs + ((size_t)(g * 16 + pm) * TT + t) * 1024 + s * 16 + j2) = hb01;
  }
}

// ---- policy head: logits[16384,64] + softmax, fused ----
__global__ __launch_bounds__(512, 1) void act1_softmax(const unsigned short* __restrict__ Aa,
    const unsigned short* __restrict__ W1, const float* __restrict__ b1,
    float* __restrict__ out) {
  __shared__ unsigned short wl[64 * 512];
  const int tid = threadIdx.x;
  #pragma unroll
  for (int r = 0; r < 8; r++) {
    int e = r * 512 + tid;
    int col = e >> 6, kc = e & 63;
    *(uint4*)(wl + ((size_t)kc * 64 + col) * 8) = *(const uint4*)(W1 + (size_t)col * 512 + kc * 8);
  }
  __syncthreads();
  const int l = tid & 63, w = tid >> 6;
  size_t row = (size_t)blockIdx.x * 8 + w;
  const unsigned short* ar = Aa + row * 512;
  float acc = 0.f;
  for (int kc = 0; kc < 64; kc++) {
    uint4 au = *(const uint4*)(ar + kc * 8);
    uint4 wu = *(const uint4*)(wl + ((size_t)kc * 64 + l) * 8);
    acc = dot8(au, wu, acc);
  }
  float logit = acc + b1[l];
  float mx = logit;
  #pragma unroll
  for (int off = 32; off >= 1; off >>= 1) mx = fmaxf(mx, __shfl_xor(mx, off));
  float e = __expf(logit - mx);
  float ssum = e;
  #pragma unroll
  for (int off = 32; off >= 1; off >>= 1) ssum += __shfl_xor(ssum, off);
  out[row * 64 + l] = e / ssum;
}

// ---- value head: wave-per-row dot over K=512 ----
__global__ __launch_bounds__(256, 4) void val1_kernel(const unsigned short* __restrict__ V,
    const unsigned short* __restrict__ w1, const float* __restrict__ b1,
    float* __restrict__ out) {
  const int tid = threadIdx.x;
  const int l = tid & 63, w = tid >> 6;
  size_t row = (size_t)blockIdx.x * 4 + w;
  uint4 vu = *(const uint4*)(V + row * 512 + l * 8);
  uint4 wu = *(const uint4*)(w1 + l * 8);
  float s = dot8(vu, wu, 0.f);
  #pragma unroll
  for (int off = 32; off >= 1; off >>= 1) s += __shfl_xor(s, off);
  if (l == 0) out[1048576u + row] = s + b1[0];
}

extern "C" void kernel_launch(void* const* d_in, const int* in_sizes, int n_in,
                              void* d_out, int out_size, void* d_ws, size_t ws_size,
                              hipStream_t stream) {
  (void)in_sizes; (void)n_in; (void)out_size;
  if (ws_size < WS_NEED) return;
  const float* x   = (const float*)d_in[0];
  const float* pw0 = (const float*)d_in[1];
  const float* pb0 = (const float*)d_in[2];
  const float* pw1 = (const float*)d_in[3];
  const float* pb1 = (const float*)d_in[4];
  const float* wih = (const float*)d_in[5];
  const float* whh = (const float*)d_in[6];
  const float* bih = (const float*)d_in[7];
  const float* bhh = (const float*)d_in[8];
  const float* aw0 = (const float*)d_in[9];
  const float* ab0 = (const float*)d_in[10];
  const float* aw1 = (const float*)d_in[11];
  const float* ab1 = (const float*)d_in[12];
  const float* vw0 = (const float*)d_in[13];
  const float* vb0 = (const float*)d_in[14];
  const float* vw1 = (const float*)d_in[15];
  const float* vb1 = (const float*)d_in[16];
  unsigned char* ws = (unsigned char*)d_ws;
  float* out = (float*)d_out;

  const unsigned short* xb   = (const unsigned short*)(ws + O_XB);
  const unsigned short* w0b  = (const unsigned short*)(ws + O_W0);
  const unsigned short* w1b  = (const unsigned short*)(ws + O_W1);
  const unsigned short* wihb = (const unsigned short*)(ws + O_WIH);
  const unsigned short* whhb = (const unsigned short*)(ws + O_WHH);
  const unsigned short* wa0b = (const unsigned short*)(ws + O_WA0);
  const unsigned short* wa1b = (const unsigned short*)(ws + O_WA1);
  const unsigned short* wv0b = (const unsigned short*)(ws + O_WV0);
  const unsigned short* wv1b = (const unsigned short*)(ws + O_WV1);
  const float* gbp = (const float*)(ws + O_GB);
  unsigned short* h1b = (unsigned short*)(ws + O_H1);
  unsigned short* ub  = (unsigned short*)(ws + O_U);
  unsigned short* gxb = (unsigned short*)(ws + O_GX);
  unsigned short* hsb = (unsigned short*)(ws + O_HS);
  unsigned* pkb = (unsigned*)(ws + O_H1);   // h bufs + flags in dead h1 region
  unsigned short* aab = h1b;                // act0 output (after scan)
  unsigned short* vvb = ub;                 // val0 output

  cvt_kernel<<<11685, 256, 0, stream>>>(x, pw0, pw1, wih, whh, aw0, aw1, vw0, vw1, bih, bhh, ws);
  gemm_bt<1, 0><<<dim3(4, 128), 256, 0, stream>>>(xb, w0b, pb0, h1b, 16384, 512, 256);
  gemm_bt<0, 0><<<dim3(4, 128), 256, 0, stream>>>(h1b, w1b, pb1, ub, 16384, 512, 512);
  gemm_bt<0, 1><<<dim3(32, 128), 256, 0, stream>>>(ub, wihb, gbp, gxb, 16384, 4096, 512);
  // zero h buffers (initial h=0) + flags (4*8192*4 + 4096 bytes)
  hipMemsetAsync(ws + O_H1, 0, 135168, stream);
  {
    const unsigned short* a_whh = whhb;
    const unsigned short* a_gx  = gxb;
    unsigned*       a_pk = pkb;
    unsigned short* a_hs = hsb;
    void* args[4] = { (void*)&a_whh, (void*)&a_gx, (void*)&a_pk, (void*)&a_hs };
    hipLaunchCooperativeKernel((void*)lstm_scan, dim3(128), dim3(256), args, 0, stream);
  }
  gemm_bt<1, 0><<<dim3(4, 128), 256, 0, stream>>>(hsb, wa0b, ab0, aab, 16384, 512, 1024);
  gemm_bt<1, 0><<<dim3(4, 128), 256, 0, stream>>>(hsb, wv0b, vb0, vvb, 16384, 512, 1024);
  act1_softmax<<<2048, 512, 0, stream>>>(aab, wa1b, ab1, out);
  val1_kernel<<<4096, 256, 0, stream>>>(vvb, wv1b, vb1, out);
}